// Round 6
// baseline (414.742 us; speedup 1.0000x reference)
//
#include <hip/hip_runtime.h>
#include <stdint.h>

#define Bsz 2
#define Sseq 2048
#define Hdim 2048
#define NH 32
#define NKV 8
#define HD 64
#define RANKD 16
#define LSCALE (1.0f/16.0f)
#define Mrows (Bsz*Sseq)      // 4096
#define NQKV 3072             // 2048 q + 512 k + 512 v

typedef unsigned short u16;
typedef __bf16 bf16x8 __attribute__((ext_vector_type(8)));
typedef float f32x4 __attribute__((ext_vector_type(4)));
typedef float f32x16 __attribute__((ext_vector_type(16)));

#define MFMA32(A, B, C) __builtin_amdgcn_mfma_f32_32x32x16_bf16(A, B, C, 0, 0, 0)

__device__ __forceinline__ u16 f2bf(float f) {
  union { float f; uint32_t u; } v; v.f = f;
  uint32_t u = v.u;
  return (u16)((u + 0x7fffu + ((u >> 16) & 1u)) >> 16);   // round-nearest-even
}
__device__ __forceinline__ float bf2f(u16 b) {
  union { uint32_t u; float f; } v; v.u = ((uint32_t)b) << 16;
  return v.f;
}

#define GLD_LDS16(g, l) \
  __builtin_amdgcn_global_load_lds((const __attribute__((address_space(1))) void*)(g), \
                                   (__attribute__((address_space(3))) void*)(l), 16, 0, 0)

// ---------------- f32 -> bf16 convert (x) ----------------
__global__ void cvt_bf16_kernel(const float* __restrict__ in, u16* __restrict__ out, int n4) {
  int i = blockIdx.x * 256 + threadIdx.x;
  if (i >= n4) return;
  float4 v = ((const float4*)in)[i];
  ushort4 o;
  o.x = f2bf(v.x); o.y = f2bf(v.y); o.z = f2bf(v.z); o.w = f2bf(v.w);
  ((ushort4*)out)[i] = o;
}

// ---------------- W_eff = W + SCALE * (A@B)^T  (bf16 out) ----------------
__global__ void weff_kernel(const float* __restrict__ W, const float* __restrict__ A,
                            const float* __restrict__ Bm, u16* __restrict__ out,
                            int N, int K) {
  __shared__ float bcol[RANKD];
  int k = blockIdx.x * 256 + threadIdx.x;
  int n = blockIdx.y;
  if (threadIdx.x < RANKD) bcol[threadIdx.x] = Bm[threadIdx.x * N + n];
  __syncthreads();
  float acc = 0.f;
#pragma unroll
  for (int r = 0; r < RANKD; ++r) acc += A[k * RANKD + r] * bcol[r];
  out[(size_t)n * K + k] = f2bf(W[(size_t)n * K + k] + acc * LSCALE);
}

// ---------------- bf16 GEMM, B-transposed layout (m97 structure) ----------------
template <typename OutT>
__global__ __launch_bounds__(256) void gemm_bt(const u16* __restrict__ A,
                                               const u16* __restrict__ Bw,
                                               OutT* __restrict__ C,
                                               int M, int N, int K) {
  __shared__ u16 As[128 * 64];
  __shared__ u16 Bs[128 * 64];
  const int t = threadIdx.x, lane = t & 63, w = t >> 6;
  const int bm0 = blockIdx.x * 128, bn0 = blockIdx.y * 128;
  const int wm = (w >> 1) * 64, wn = (w & 1) * 64;
  f32x4 acc[4][4] = {};
  for (int kt = 0; kt < K; kt += 64) {
#pragma unroll
    for (int i = 0; i < 4; ++i) {
      int offw = i * 4096 + w * 1024;
      int offl = offw + lane * 16;
      int row = offl >> 7;
      int cb  = offl & 127;
      const u16* ga = A  + (size_t)(bm0 + row) * K + kt + (cb >> 1);
      GLD_LDS16(ga, (char*)As + offw);
      const u16* gb = Bw + (size_t)(bn0 + row) * K + kt + (cb >> 1);
      GLD_LDS16(gb, (char*)Bs + offw);
    }
    __syncthreads();
#pragma unroll
    for (int kk = 0; kk < 2; ++kk) {
      const int col = kk * 32 + (lane >> 4) * 8;
      bf16x8 af[4], bfr[4];
#pragma unroll
      for (int mi = 0; mi < 4; ++mi)
        af[mi] = *(const bf16x8*)&As[(wm + mi * 16 + (lane & 15)) * 64 + col];
#pragma unroll
      for (int ni = 0; ni < 4; ++ni)
        bfr[ni] = *(const bf16x8*)&Bs[(wn + ni * 16 + (lane & 15)) * 64 + col];
#pragma unroll
      for (int mi = 0; mi < 4; ++mi)
#pragma unroll
        for (int ni = 0; ni < 4; ++ni)
          acc[mi][ni] = __builtin_amdgcn_mfma_f32_16x16x32_bf16(af[mi], bfr[ni], acc[mi][ni], 0, 0, 0);
    }
    __syncthreads();
  }
  const int r0 = (lane >> 4) * 4, cq = lane & 15;
#pragma unroll
  for (int mi = 0; mi < 4; ++mi)
#pragma unroll
    for (int ni = 0; ni < 4; ++ni) {
      size_t base = (size_t)(bm0 + wm + mi * 16 + r0) * N + bn0 + wn + ni * 16 + cq;
#pragma unroll
      for (int r = 0; r < 4; ++r) {
        float v = acc[mi][ni][r];
        if constexpr (sizeof(OutT) == 2) C[base + (size_t)r * N] = f2bf(v);
        else                             C[base + (size_t)r * N] = v;
      }
    }
}

// ---------------- RoPE q: qkv bf16 [M,3072] -> qb bf16 [B,NH,S,HD] ----------------
__global__ void rope_q_kernel(const u16* __restrict__ qkv, const int* __restrict__ pid,
                              u16* __restrict__ qb) {
  int idx = blockIdx.x * 256 + threadIdx.x;
  int i = idx & 31;
  int s = (idx >> 5) & (Sseq - 1);
  int h = (idx >> 16) & (NH - 1);
  int b = idx >> 21;
  int row = b * Sseq + s;
  const u16* src = qkv + (size_t)row * NQKV + h * HD + i;
  float q0 = bf2f(src[0]);
  float q1 = bf2f(src[32]);
  float pos = (float)pid[row];
  float ang = pos * expf(-(float)i * (9.210340371976184f / 32.f));
  float c = cosf(ang), sn = sinf(ang);
  u16* dst = qb + ((size_t)(b * NH + h) * Sseq + s) * HD + i;
  dst[0]  = f2bf(q0 * c - q1 * sn);
  dst[32] = f2bf(q1 * c + q0 * sn);
}

// ---------------- RoPE k (pre-scaled by log2(e)/sqrt(HD)): -> kb bf16 [B,NKV,S,HD] --
__global__ void rope_k_kernel(const u16* __restrict__ qkv, const int* __restrict__ pid,
                              u16* __restrict__ kb) {
  const float SCK = 0.18033688011112042f;  // log2(e)/8
  int idx = blockIdx.x * 256 + threadIdx.x;
  int i = idx & 31;
  int s = (idx >> 5) & (Sseq - 1);
  int h = (idx >> 16) & (NKV - 1);
  int b = idx >> 19;
  int row = b * Sseq + s;
  const u16* src = qkv + (size_t)row * NQKV + 2048 + h * HD + i;
  float q0 = bf2f(src[0]);
  float q1 = bf2f(src[32]);
  float pos = (float)pid[row];
  float ang = pos * expf(-(float)i * (9.210340371976184f / 32.f));
  float c = cosf(ang), sn = sinf(ang);
  u16* dst = kb + ((size_t)(b * NKV + h) * Sseq + s) * HD + i;
  dst[0]  = f2bf((q0 * c - q1 * sn) * SCK);
  dst[32] = f2bf((q1 * c + q0 * sn) * SCK);
}

// ---------------- V transpose: qkv bf16 -> vT bf16 [B,NKV,HD,S] ----------------
__global__ void pack_vT_kernel(const u16* __restrict__ qkv, u16* __restrict__ vT) {
  __shared__ u16 tile[64][72];
  int bh = blockIdx.y;
  int s0 = blockIdx.x * 64;
  int b = bh >> 3, hkv = bh & 7;
  int t = threadIdx.x;
#pragma unroll
  for (int ii = 0; ii < 16; ++ii) {
    int lin = ii * 256 + t;
    int sl = lin >> 6, d = lin & 63;
    tile[sl][d] = qkv[(size_t)(b * Sseq + s0 + sl) * NQKV + 2560 + hkv * HD + d];
  }
  __syncthreads();
#pragma unroll
  for (int ii = 0; ii < 16; ++ii) {
    int lin = ii * 256 + t;
    int d = lin >> 6, sl = lin & 63;
    vT[((size_t)bh * HD + d) * Sseq + s0 + sl] = tile[sl][d];
  }
}

// ---------------- flash attention step ----------------
template <bool MASKED>
__device__ __forceinline__ void attn_step(int k0, int qg, int hi, int q,
                                          const u16* __restrict__ kbp,
                                          const u16* __restrict__ vbp,
                                          const bf16x8 (&qf)[4],
                                          f32x16& o0, f32x16& o1,
                                          float& m, float& lsum) {
  bf16x8 kf0[4], kf1[4];
#pragma unroll
  for (int dk = 0; dk < 4; ++dk) {
    const u16* kp = kbp + (size_t)(k0 + q) * HD + dk * 16 + hi * 8;
    kf0[dk] = *(const bf16x8*)kp;
    kf1[dk] = *(const bf16x8*)(kp + 32 * HD);
  }
  f32x16 st0 = {}, st1 = {};
#pragma unroll
  for (int dk = 0; dk < 4; ++dk) {
    st0 = MFMA32(kf0[dk], qf[dk], st0);
    st1 = MFMA32(kf1[dk], qf[dk], st1);
  }
  bf16x8 vf0[4], vf1[4];
#pragma unroll
  for (int ks = 0; ks < 4; ++ks) {
    const u16* vp = vbp + (size_t)q * Sseq + k0 + ks * 16 + hi * 8;
    vf0[ks] = *(const bf16x8*)vp;
    vf1[ks] = *(const bf16x8*)(vp + 32 * Sseq);
  }
  if (MASKED) {
#pragma unroll
    for (int r = 0; r < 16; ++r) {
      const int koff = (r & 3) + 8 * (r >> 2) + 4 * hi;
      if (k0 + koff > qg)      st0[r] = -3.0e38f;
      if (k0 + 32 + koff > qg) st1[r] = -3.0e38f;
    }
  }
  // tree-reduce max (depth 5, ILP); per-half only — cross-half shfl deferred
  float t01[16];
#pragma unroll
  for (int r = 0; r < 16; ++r) t01[r] = fmaxf(st0[r], st1[r]);
#pragma unroll
  for (int s = 8; s > 0; s >>= 1)
#pragma unroll
    for (int r = 0; r < s; ++r) t01[r] = fmaxf(t01[r], t01[r + s]);
  float tmax = t01[0];
  // __any spans all 64 lanes, so the per-half tmax check catches either half.
  // The expensive cross-half shfl runs only in the (rare) rescale branch; both
  // halves compute the same mnew there, so m stays wave-uniform.
  if (__any(tmax > m + 8.f)) {                // defer-max (T13)
    float tx = fmaxf(tmax, __shfl_xor(tmax, 32));
    float mnew = fmaxf(m, tx);
    float al = exp2f(m - mnew);
    lsum *= al;
#pragma unroll
    for (int r = 0; r < 16; ++r) { o0[r] *= al; o1[r] *= al; }
    m = mnew;
  }
  float ps[16];
#pragma unroll
  for (int r = 0; r < 16; ++r) {
    float e0 = exp2f(st0[r] - m), e1 = exp2f(st1[r] - m);
    st0[r] = e0; st1[r] = e1;
    ps[r] = e0 + e1;
  }
#pragma unroll
  for (int s = 8; s > 0; s >>= 1)
#pragma unroll
    for (int r = 0; r < s; ++r) ps[r] += ps[r + s];
  lsum += ps[0];                 // lane-partial; cross-half combine deferred to epilogue
  // P -> bf16 fragments via cvt_pk + permlane32_swap (T12; round-2-proven pattern)
  bf16x8 pa[4];
#pragma unroll
  for (int ks = 0; ks < 4; ++ks) {
    const int sel = (ks & 1) * 8;
    f32x16& stt = (ks < 2) ? st0 : st1;
    uint32_t X0, Y0, X1, Y1;
    asm("v_cvt_pk_bf16_f32 %0, %1, %2" : "=v"(X0) : "v"(stt[sel + 0]), "v"(stt[sel + 1]));
    asm("v_cvt_pk_bf16_f32 %0, %1, %2" : "=v"(Y0) : "v"(stt[sel + 4]), "v"(stt[sel + 5]));
    asm("v_cvt_pk_bf16_f32 %0, %1, %2" : "=v"(X1) : "v"(stt[sel + 2]), "v"(stt[sel + 3]));
    asm("v_cvt_pk_bf16_f32 %0, %1, %2" : "=v"(Y1) : "v"(stt[sel + 6]), "v"(stt[sel + 7]));
    asm volatile("v_permlane32_swap_b32 %0, %1" : "+v"(X0), "+v"(Y0));
    asm volatile("v_permlane32_swap_b32 %0, %1" : "+v"(X1), "+v"(Y1));
    union { uint32_t w[4]; bf16x8 v; } u_;
    u_.w[0] = X0; u_.w[1] = X1; u_.w[2] = Y0; u_.w[3] = Y1;
    pa[ks] = u_.v;
  }
#pragma unroll
  for (int ks = 0; ks < 4; ++ks) {
    o0 = MFMA32(vf0[ks], pa[ks], o0);
    o1 = MFMA32(vf1[ks], pa[ks], o1);
  }
}

// 4 waves/block, 32 q-rows/wave, 64-key tiles.
// Work map matched to HW dispatch (XCD = bid%8, CU slots fill by bid/8):
// qt = (k&1) ? k>>1 : 63-(k>>1) with k = bid>>3, so any 4 consecutive k
// (one CU's resident blocks) alternate heavy/light and sum to ~66.5 steps.
__global__ __launch_bounds__(256) void attn_kernel(const u16* __restrict__ qb,
                                                   const u16* __restrict__ kb,
                                                   const u16* __restrict__ vT,
                                                   u16* __restrict__ aout) {
  __shared__ uint32_t ldso[4][32 * 33];
  const int tid = threadIdx.x;
  const int lane = tid & 63, wid = tid >> 6;
  const int q = lane & 31, hi = lane >> 5;
  const int bid = blockIdx.x;
  const int kk_ = bid >> 3, x_ = bid & 7;
  const int s_ = kk_ >> 1, par = kk_ & 1;
  const int qt = par ? s_ : 63 - s_;
  const int bh = (((x_ << 1) | par) << 2) | wid;
  const int b = bh >> 5, h = bh & 31, hkv = h >> 2;
  const int qbase = qt * 32, qg = qbase + q;

  const u16* qp = qb + ((size_t)bh * Sseq + qg) * HD + hi * 8;
  bf16x8 qf[4];
#pragma unroll
  for (int dk = 0; dk < 4; ++dk) qf[dk] = *(const bf16x8*)(qp + dk * 16);

  const u16* kbp = kb + (size_t)(b * NKV + hkv) * Sseq * HD;
  const u16* vbp = vT + (size_t)(b * NKV + hkv) * HD * Sseq;

  f32x16 o0 = {}, o1 = {};
  float m = -INFINITY, lsum = 0.f;
  const int ntiles = (qt >> 1) + 1;

  for (int kt = 0; kt < ntiles - 1; ++kt)
    attn_step<false>(kt * 64, qg, hi, q, kbp, vbp, qf, o0, o1, m, lsum);
  attn_step<true>((ntiles - 1) * 64, qg, hi, q, kbp, vbp, qf, o0, o1, m, lsum);

  lsum += __shfl_xor(lsum, 32);        // cross-half lsum combine (round-2-proven)
  const float inv = 1.f / lsum;

  // epilogue transpose via packed-bf16 u32 LDS (16.9 KB/block)
  uint32_t* lw = ldso[wid];
#pragma unroll
  for (int rr = 0; rr < 16; rr += 2) {
    const int d2 = ((rr >> 1) & 1) + 4 * (rr >> 2) + 2 * hi;
    uint32_t w0, w1;
    asm("v_cvt_pk_bf16_f32 %0, %1, %2" : "=v"(w0) : "v"(o0[rr] * inv), "v"(o0[rr + 1] * inv));
    asm("v_cvt_pk_bf16_f32 %0, %1, %2" : "=v"(w1) : "v"(o1[rr] * inv), "v"(o1[rr + 1] * inv));
    lw[d2 * 33 + q]        = w0;
    lw[(16 + d2) * 33 + q] = w1;
  }
  asm volatile("s_waitcnt lgkmcnt(0)" ::: "memory");
  __builtin_amdgcn_sched_barrier(0);
  uint32_t wv[16];
#pragma unroll
  for (int jj = 0; jj < 16; ++jj) wv[jj] = lw[(hi * 16 + jj) * 33 + q];
  uint4* op4 = (uint4*)(aout + (size_t)(b * Sseq + qbase + q) * (NH * HD) + h * HD + hi * 32);
#pragma unroll
  for (int k4 = 0; k4 < 4; ++k4)
    op4[k4] = make_uint4(wv[4 * k4], wv[4 * k4 + 1], wv[4 * k4 + 2], wv[4 * k4 + 3]);
}

extern "C" void kernel_launch(void* const* d_in, const int* in_sizes, int n_in,
                              void* d_out, int out_size, void* d_ws, size_t ws_size,
                              hipStream_t stream) {
  const float* x  = (const float*)d_in[0];
  const int*   pid= (const int*)d_in[1];
  const float* Wq = (const float*)d_in[2];
  const float* Wk = (const float*)d_in[3];
  const float* Wv = (const float*)d_in[4];
  const float* Wo = (const float*)d_in[5];
  const float* Aq = (const float*)d_in[6];
  const float* Bq = (const float*)d_in[7];
  const float* Ak = (const float*)d_in[8];
  const float* Bk = (const float*)d_in[9];
  const float* Av = (const float*)d_in[10];
  const float* Bv = (const float*)d_in[11];
  const float* Ao = (const float*)d_in[12];
  const float* Bo = (const float*)d_in[13];
  float* out = (float*)d_out;

  char* w = (char*)d_ws;
  u16*   x_bf    = (u16*)w;   w += (size_t)Mrows * Hdim * 2;
  u16*   weffqkv = (u16*)w;   w += (size_t)NQKV * Hdim * 2;
  u16*   weffo   = (u16*)w;   w += (size_t)Hdim * Hdim * 2;
  u16*   qkv     = (u16*)w;   w += (size_t)Mrows * NQKV * 2;
  u16*   qbb     = (u16*)w;   w += (size_t)Bsz * NH * Sseq * HD * 2;
  u16*   kbb     = (u16*)w;   w += (size_t)Bsz * NKV * Sseq * HD * 2;
  u16*   vTb     = (u16*)w;   w += (size_t)Bsz * NKV * Sseq * HD * 2;
  u16*   aoutb   = (u16*)w;   w += (size_t)Mrows * (NH * HD) * 2;

  cvt_bf16_kernel<<<8192, 256, 0, stream>>>(x, x_bf, Mrows * Hdim / 4);

  weff_kernel<<<dim3(8, 2048), 256, 0, stream>>>(Wq, Aq, Bq, weffqkv, 2048, 2048);
  weff_kernel<<<dim3(8, 512),  256, 0, stream>>>(Wk, Ak, Bk, weffqkv + (size_t)2048 * 2048, 512, 2048);
  weff_kernel<<<dim3(8, 512),  256, 0, stream>>>(Wv, Av, Bv, weffqkv + (size_t)2560 * 2048, 512, 2048);
  weff_kernel<<<dim3(8, 2048), 256, 0, stream>>>(Wo, Ao, Bo, weffo, 2048, 2048);

  gemm_bt<u16><<<dim3(32, 24), 256, 0, stream>>>(x_bf, weffqkv, qkv, Mrows, NQKV, Hdim);

  rope_q_kernel<<<16384, 256, 0, stream>>>(qkv, pid, qbb);
  rope_k_kernel<<<4096, 256, 0, stream>>>(qkv, pid, kbb);
  pack_vT_kernel<<<dim3(32, 16), 256, 0, stream>>>(qkv, vTb);

  attn_kernel<<<1024, 256, 0, stream>>>(qbb, kbb, vTb, aoutb);

  gemm_bt<float><<<dim3(32, 16), 256, 0, stream>>>(aoutb, weffo, out, Mrows, 2048, 2048);
}

// Round 7
// 345.466 us; speedup vs baseline: 1.2005x; 1.2005x over previous
//
#include <hip/hip_runtime.h>
#include <stdint.h>

#define Bsz 2
#define Sseq 2048
#define Hdim 2048
#define NH 32
#define NKV 8
#define HD 64
#define RANKD 16
#define LSCALE (1.0f/16.0f)
#define Mrows (Bsz*Sseq)      // 4096
#define NQKV 3072             // 2048 q + 512 k + 512 v

typedef unsigned short u16;
typedef __bf16 bf16x8 __attribute__((ext_vector_type(8)));
typedef float f32x4 __attribute__((ext_vector_type(4)));
typedef float f32x16 __attribute__((ext_vector_type(16)));

#define MFMA32(A, B, C) __builtin_amdgcn_mfma_f32_32x32x16_bf16(A, B, C, 0, 0, 0)

__device__ __forceinline__ u16 f2bf(float f) {
  union { float f; uint32_t u; } v; v.f = f;
  uint32_t u = v.u;
  return (u16)((u + 0x7fffu + ((u >> 16) & 1u)) >> 16);   // round-nearest-even
}
__device__ __forceinline__ float bf2f(u16 b) {
  union { uint32_t u; float f; } v; v.u = ((uint32_t)b) << 16;
  return v.f;
}

#define GLD_LDS16(g, l) \
  __builtin_amdgcn_global_load_lds((const __attribute__((address_space(1))) void*)(g), \
                                   (__attribute__((address_space(3))) void*)(l), 16, 0, 0)

// ---------------- f32 -> bf16 convert (x) ----------------
__global__ void cvt_bf16_kernel(const float* __restrict__ in, u16* __restrict__ out, int n4) {
  int i = blockIdx.x * 256 + threadIdx.x;
  if (i >= n4) return;
  float4 v = ((const float4*)in)[i];
  ushort4 o;
  o.x = f2bf(v.x); o.y = f2bf(v.y); o.z = f2bf(v.z); o.w = f2bf(v.w);
  ((ushort4*)out)[i] = o;
}

// ---------------- W_eff = W + SCALE * (A@B)^T  (bf16 out) ----------------
__global__ void weff_kernel(const float* __restrict__ W, const float* __restrict__ A,
                            const float* __restrict__ Bm, u16* __restrict__ out,
                            int N, int K) {
  __shared__ float bcol[RANKD];
  int k = blockIdx.x * 256 + threadIdx.x;
  int n = blockIdx.y;
  if (threadIdx.x < RANKD) bcol[threadIdx.x] = Bm[threadIdx.x * N + n];
  __syncthreads();
  float acc = 0.f;
#pragma unroll
  for (int r = 0; r < RANKD; ++r) acc += A[k * RANKD + r] * bcol[r];
  out[(size_t)n * K + k] = f2bf(W[(size_t)n * K + k] + acc * LSCALE);
}

// ---------------- bf16 GEMM, B-transposed layout (m97 structure) ----------------
template <typename OutT>
__global__ __launch_bounds__(256) void gemm_bt(const u16* __restrict__ A,
                                               const u16* __restrict__ Bw,
                                               OutT* __restrict__ C,
                                               int M, int N, int K) {
  __shared__ u16 As[128 * 64];
  __shared__ u16 Bs[128 * 64];
  const int t = threadIdx.x, lane = t & 63, w = t >> 6;
  const int bm0 = blockIdx.x * 128, bn0 = blockIdx.y * 128;
  const int wm = (w >> 1) * 64, wn = (w & 1) * 64;
  f32x4 acc[4][4] = {};
  for (int kt = 0; kt < K; kt += 64) {
#pragma unroll
    for (int i = 0; i < 4; ++i) {
      int offw = i * 4096 + w * 1024;
      int offl = offw + lane * 16;
      int row = offl >> 7;
      int cb  = offl & 127;
      const u16* ga = A  + (size_t)(bm0 + row) * K + kt + (cb >> 1);
      GLD_LDS16(ga, (char*)As + offw);
      const u16* gb = Bw + (size_t)(bn0 + row) * K + kt + (cb >> 1);
      GLD_LDS16(gb, (char*)Bs + offw);
    }
    __syncthreads();
#pragma unroll
    for (int kk = 0; kk < 2; ++kk) {
      const int col = kk * 32 + (lane >> 4) * 8;
      bf16x8 af[4], bfr[4];
#pragma unroll
      for (int mi = 0; mi < 4; ++mi)
        af[mi] = *(const bf16x8*)&As[(wm + mi * 16 + (lane & 15)) * 64 + col];
#pragma unroll
      for (int ni = 0; ni < 4; ++ni)
        bfr[ni] = *(const bf16x8*)&Bs[(wn + ni * 16 + (lane & 15)) * 64 + col];
#pragma unroll
      for (int mi = 0; mi < 4; ++mi)
#pragma unroll
        for (int ni = 0; ni < 4; ++ni)
          acc[mi][ni] = __builtin_amdgcn_mfma_f32_16x16x32_bf16(af[mi], bfr[ni], acc[mi][ni], 0, 0, 0);
    }
    __syncthreads();
  }
  const int r0 = (lane >> 4) * 4, cq = lane & 15;
#pragma unroll
  for (int mi = 0; mi < 4; ++mi)
#pragma unroll
    for (int ni = 0; ni < 4; ++ni) {
      size_t base = (size_t)(bm0 + wm + mi * 16 + r0) * N + bn0 + wn + ni * 16 + cq;
#pragma unroll
      for (int r = 0; r < 4; ++r) {
        float v = acc[mi][ni][r];
        if constexpr (sizeof(OutT) == 2) C[base + (size_t)r * N] = f2bf(v);
        else                             C[base + (size_t)r * N] = v;
      }
    }
}

// ---------------- RoPE q: qkv bf16 [M,3072] -> qb bf16 [B,NH,S,HD] ----------------
__global__ void rope_q_kernel(const u16* __restrict__ qkv, const int* __restrict__ pid,
                              u16* __restrict__ qb) {
  int idx = blockIdx.x * 256 + threadIdx.x;
  int i = idx & 31;
  int s = (idx >> 5) & (Sseq - 1);
  int h = (idx >> 16) & (NH - 1);
  int b = idx >> 21;
  int row = b * Sseq + s;
  const u16* src = qkv + (size_t)row * NQKV + h * HD + i;
  float q0 = bf2f(src[0]);
  float q1 = bf2f(src[32]);
  float pos = (float)pid[row];
  float ang = pos * expf(-(float)i * (9.210340371976184f / 32.f));
  float c = cosf(ang), sn = sinf(ang);
  u16* dst = qb + ((size_t)(b * NH + h) * Sseq + s) * HD + i;
  dst[0]  = f2bf(q0 * c - q1 * sn);
  dst[32] = f2bf(q1 * c + q0 * sn);
}

// ---------------- RoPE k (pre-scaled by log2(e)/sqrt(HD)): -> kb bf16 [B,NKV,S,HD] --
__global__ void rope_k_kernel(const u16* __restrict__ qkv, const int* __restrict__ pid,
                              u16* __restrict__ kb) {
  const float SCK = 0.18033688011112042f;  // log2(e)/8
  int idx = blockIdx.x * 256 + threadIdx.x;
  int i = idx & 31;
  int s = (idx >> 5) & (Sseq - 1);
  int h = (idx >> 16) & (NKV - 1);
  int b = idx >> 19;
  int row = b * Sseq + s;
  const u16* src = qkv + (size_t)row * NQKV + 2048 + h * HD + i;
  float q0 = bf2f(src[0]);
  float q1 = bf2f(src[32]);
  float pos = (float)pid[row];
  float ang = pos * expf(-(float)i * (9.210340371976184f / 32.f));
  float c = cosf(ang), sn = sinf(ang);
  u16* dst = kb + ((size_t)(b * NKV + h) * Sseq + s) * HD + i;
  dst[0]  = f2bf((q0 * c - q1 * sn) * SCK);
  dst[32] = f2bf((q1 * c + q0 * sn) * SCK);
}

// ---------------- V transpose: qkv bf16 -> vT bf16 [B,NKV,HD,S] ----------------
__global__ void pack_vT_kernel(const u16* __restrict__ qkv, u16* __restrict__ vT) {
  __shared__ u16 tile[64][72];
  int bh = blockIdx.y;
  int s0 = blockIdx.x * 64;
  int b = bh >> 3, hkv = bh & 7;
  int t = threadIdx.x;
#pragma unroll
  for (int ii = 0; ii < 16; ++ii) {
    int lin = ii * 256 + t;
    int sl = lin >> 6, d = lin & 63;
    tile[sl][d] = qkv[(size_t)(b * Sseq + s0 + sl) * NQKV + 2560 + hkv * HD + d];
  }
  __syncthreads();
#pragma unroll
  for (int ii = 0; ii < 16; ++ii) {
    int lin = ii * 256 + t;
    int d = lin >> 6, sl = lin & 63;
    vT[((size_t)bh * HD + d) * Sseq + s0 + sl] = tile[sl][d];
  }
}

// ---------------- flash attention step ----------------
template <bool MASKED>
__device__ __forceinline__ void attn_step(int k0, int qg, int hi, int q,
                                          const u16* __restrict__ kbp,
                                          const u16* __restrict__ vbp,
                                          const bf16x8 (&qf)[4],
                                          f32x16& o0, f32x16& o1,
                                          float& m, float& lsum) {
  bf16x8 kf0[4], kf1[4];
#pragma unroll
  for (int dk = 0; dk < 4; ++dk) {
    const u16* kp = kbp + (size_t)(k0 + q) * HD + dk * 16 + hi * 8;
    kf0[dk] = *(const bf16x8*)kp;
    kf1[dk] = *(const bf16x8*)(kp + 32 * HD);
  }
  f32x16 st0 = {}, st1 = {};
#pragma unroll
  for (int dk = 0; dk < 4; ++dk) {
    st0 = MFMA32(kf0[dk], qf[dk], st0);
    st1 = MFMA32(kf1[dk], qf[dk], st1);
  }
  bf16x8 vf0[4], vf1[4];
#pragma unroll
  for (int ks = 0; ks < 4; ++ks) {
    const u16* vp = vbp + (size_t)q * Sseq + k0 + ks * 16 + hi * 8;
    vf0[ks] = *(const bf16x8*)vp;
    vf1[ks] = *(const bf16x8*)(vp + 32 * Sseq);
  }
  if (MASKED) {
#pragma unroll
    for (int r = 0; r < 16; ++r) {
      const int koff = (r & 3) + 8 * (r >> 2) + 4 * hi;
      if (k0 + koff > qg)      st0[r] = -3.0e38f;
      if (k0 + 32 + koff > qg) st1[r] = -3.0e38f;
    }
  }
  // tree-reduce max (depth 5, ILP); per-half only — cross-half shfl deferred
  float t01[16];
#pragma unroll
  for (int r = 0; r < 16; ++r) t01[r] = fmaxf(st0[r], st1[r]);
#pragma unroll
  for (int s = 8; s > 0; s >>= 1)
#pragma unroll
    for (int r = 0; r < s; ++r) t01[r] = fmaxf(t01[r], t01[r + s]);
  float tmax = t01[0];
  // __any spans all 64 lanes, so the per-half tmax check catches either half.
  // Cross-half shfl runs only in the (rare) rescale branch; both halves compute
  // the same mnew there, so m stays wave-uniform.
  if (__any(tmax > m + 8.f)) {                // defer-max (T13)
    float tx = fmaxf(tmax, __shfl_xor(tmax, 32));
    float mnew = fmaxf(m, tx);
    float al = exp2f(m - mnew);
    lsum *= al;
#pragma unroll
    for (int r = 0; r < 16; ++r) { o0[r] *= al; o1[r] *= al; }
    m = mnew;
  }
  float ps[16];
#pragma unroll
  for (int r = 0; r < 16; ++r) {
    float e0 = exp2f(st0[r] - m), e1 = exp2f(st1[r] - m);
    st0[r] = e0; st1[r] = e1;
    ps[r] = e0 + e1;
  }
#pragma unroll
  for (int s = 8; s > 0; s >>= 1)
#pragma unroll
    for (int r = 0; r < s; ++r) ps[r] += ps[r + s];
  lsum += ps[0];                 // lane-partial; cross-half combine deferred to epilogue
  // P -> bf16 fragments via cvt_pk + permlane32_swap (T12; round-2-proven pattern)
  bf16x8 pa[4];
#pragma unroll
  for (int ks = 0; ks < 4; ++ks) {
    const int sel = (ks & 1) * 8;
    f32x16& stt = (ks < 2) ? st0 : st1;
    uint32_t X0, Y0, X1, Y1;
    asm("v_cvt_pk_bf16_f32 %0, %1, %2" : "=v"(X0) : "v"(stt[sel + 0]), "v"(stt[sel + 1]));
    asm("v_cvt_pk_bf16_f32 %0, %1, %2" : "=v"(Y0) : "v"(stt[sel + 4]), "v"(stt[sel + 5]));
    asm("v_cvt_pk_bf16_f32 %0, %1, %2" : "=v"(X1) : "v"(stt[sel + 2]), "v"(stt[sel + 3]));
    asm("v_cvt_pk_bf16_f32 %0, %1, %2" : "=v"(Y1) : "v"(stt[sel + 6]), "v"(stt[sel + 7]));
    asm volatile("v_permlane32_swap_b32 %0, %1" : "+v"(X0), "+v"(Y0));
    asm volatile("v_permlane32_swap_b32 %0, %1" : "+v"(X1), "+v"(Y1));
    union { uint32_t w[4]; bf16x8 v; } u_;
    u_.w[0] = X0; u_.w[1] = X1; u_.w[2] = Y0; u_.w[3] = Y1;
    pa[ks] = u_.v;
  }
#pragma unroll
  for (int ks = 0; ks < 4; ++ks) {
    o0 = MFMA32(vf0[ks], pa[ks], o0);
    o1 = MFMA32(vf1[ks], pa[ks], o1);
  }
}

// 4 waves/block, 32 q-rows/wave, 64-key tiles.
// Work map: ROUND-2-PROVEN — g = bid*4+wid, bh = g&63 (4 waves of a block are
// 4 consecutive heads sharing one KV head), qt = 63-(g>>6) (heavy tiles first).
// Rounds 5/6 tried "dispatch-aware" remaps; both regressed (144/204 µs vs 137).
__global__ __launch_bounds__(256) void attn_kernel(const u16* __restrict__ qb,
                                                   const u16* __restrict__ kb,
                                                   const u16* __restrict__ vT,
                                                   u16* __restrict__ aout) {
  __shared__ uint32_t ldso[4][32 * 33];
  const int tid = threadIdx.x;
  const int lane = tid & 63, wid = tid >> 6;
  const int q = lane & 31, hi = lane >> 5;
  const int g = blockIdx.x * 4 + wid;
  const int bh = g & 63;
  const int qt = 63 - (g >> 6);
  const int b = bh >> 5, h = bh & 31, hkv = h >> 2;
  const int qbase = qt * 32, qg = qbase + q;

  const u16* qp = qb + ((size_t)bh * Sseq + qg) * HD + hi * 8;
  bf16x8 qf[4];
#pragma unroll
  for (int dk = 0; dk < 4; ++dk) qf[dk] = *(const bf16x8*)(qp + dk * 16);

  const u16* kbp = kb + (size_t)(b * NKV + hkv) * Sseq * HD;
  const u16* vbp = vT + (size_t)(b * NKV + hkv) * HD * Sseq;

  f32x16 o0 = {}, o1 = {};
  float m = -INFINITY, lsum = 0.f;
  const int ntiles = (qt >> 1) + 1;

  for (int kt = 0; kt < ntiles - 1; ++kt)
    attn_step<false>(kt * 64, qg, hi, q, kbp, vbp, qf, o0, o1, m, lsum);
  attn_step<true>((ntiles - 1) * 64, qg, hi, q, kbp, vbp, qf, o0, o1, m, lsum);

  lsum += __shfl_xor(lsum, 32);        // cross-half lsum combine (round-2-proven)
  const float inv = 1.f / lsum;

  // epilogue transpose via packed-bf16 u32 LDS (16.9 KB/block)
  uint32_t* lw = ldso[wid];
#pragma unroll
  for (int rr = 0; rr < 16; rr += 2) {
    const int d2 = ((rr >> 1) & 1) + 4 * (rr >> 2) + 2 * hi;
    uint32_t w0, w1;
    asm("v_cvt_pk_bf16_f32 %0, %1, %2" : "=v"(w0) : "v"(o0[rr] * inv), "v"(o0[rr + 1] * inv));
    asm("v_cvt_pk_bf16_f32 %0, %1, %2" : "=v"(w1) : "v"(o1[rr] * inv), "v"(o1[rr + 1] * inv));
    lw[d2 * 33 + q]        = w0;
    lw[(16 + d2) * 33 + q] = w1;
  }
  asm volatile("s_waitcnt lgkmcnt(0)" ::: "memory");
  __builtin_amdgcn_sched_barrier(0);
  uint32_t wv[16];
#pragma unroll
  for (int jj = 0; jj < 16; ++jj) wv[jj] = lw[(hi * 16 + jj) * 33 + q];
  uint4* op4 = (uint4*)(aout + (size_t)(b * Sseq + qbase + q) * (NH * HD) + h * HD + hi * 32);
#pragma unroll
  for (int k4 = 0; k4 < 4; ++k4)
    op4[k4] = make_uint4(wv[4 * k4], wv[4 * k4 + 1], wv[4 * k4 + 2], wv[4 * k4 + 3]);
}

extern "C" void kernel_launch(void* const* d_in, const int* in_sizes, int n_in,
                              void* d_out, int out_size, void* d_ws, size_t ws_size,
                              hipStream_t stream) {
  const float* x  = (const float*)d_in[0];
  const int*   pid= (const int*)d_in[1];
  const float* Wq = (const float*)d_in[2];
  const float* Wk = (const float*)d_in[3];
  const float* Wv = (const float*)d_in[4];
  const float* Wo = (const float*)d_in[5];
  const float* Aq = (const float*)d_in[6];
  const float* Bq = (const float*)d_in[7];
  const float* Ak = (const float*)d_in[8];
  const float* Bk = (const float*)d_in[9];
  const float* Av = (const float*)d_in[10];
  const float* Bv = (const float*)d_in[11];
  const float* Ao = (const float*)d_in[12];
  const float* Bo = (const float*)d_in[13];
  float* out = (float*)d_out;

  char* w = (char*)d_ws;
  u16*   x_bf    = (u16*)w;   w += (size_t)Mrows * Hdim * 2;
  u16*   weffqkv = (u16*)w;   w += (size_t)NQKV * Hdim * 2;
  u16*   weffo   = (u16*)w;   w += (size_t)Hdim * Hdim * 2;
  u16*   qkv     = (u16*)w;   w += (size_t)Mrows * NQKV * 2;
  u16*   qbb     = (u16*)w;   w += (size_t)Bsz * NH * Sseq * HD * 2;
  u16*   kbb     = (u16*)w;   w += (size_t)Bsz * NKV * Sseq * HD * 2;
  u16*   vTb     = (u16*)w;   w += (size_t)Bsz * NKV * Sseq * HD * 2;
  u16*   aoutb   = (u16*)w;   w += (size_t)Mrows * (NH * HD) * 2;

  cvt_bf16_kernel<<<8192, 256, 0, stream>>>(x, x_bf, Mrows * Hdim / 4);

  weff_kernel<<<dim3(8, 2048), 256, 0, stream>>>(Wq, Aq, Bq, weffqkv, 2048, 2048);
  weff_kernel<<<dim3(8, 512),  256, 0, stream>>>(Wk, Ak, Bk, weffqkv + (size_t)2048 * 2048, 512, 2048);
  weff_kernel<<<dim3(8, 512),  256, 0, stream>>>(Wv, Av, Bv, weffqkv + (size_t)2560 * 2048, 512, 2048);
  weff_kernel<<<dim3(8, 2048), 256, 0, stream>>>(Wo, Ao, Bo, weffo, 2048, 2048);

  gemm_bt<u16><<<dim3(32, 24), 256, 0, stream>>>(x_bf, weffqkv, qkv, Mrows, NQKV, Hdim);

  rope_q_kernel<<<16384, 256, 0, stream>>>(qkv, pid, qbb);
  rope_k_kernel<<<4096, 256, 0, stream>>>(qkv, pid, kbb);
  pack_vT_kernel<<<dim3(32, 16), 256, 0, stream>>>(qkv, vTb);

  attn_kernel<<<1024, 256, 0, stream>>>(qbb, kbb, vTb, aoutb);

  gemm_bt<float><<<dim3(32, 16), 256, 0, stream>>>(aoutb, weffo, out, Mrows, 2048, 2048);
}